// Round 1
// baseline (14251.547 us; speedup 1.0000x reference)
//
#include <hip/hip_runtime.h>
#include <hip/hip_bf16.h>
#include <math.h>

#define B_ 64
#define T_ 48
#define D_ 16
#define H_ 128
#define NU_ 128
#define HEADS_ 8
#define HD_ 16
#define P_ 240
#define KK_ 272
#define LAM_ 0.01f
#define THR_ 0.01f

// output offsets (floats)
#define NSTEP_OUT 44
#define OFF_A (B_*NSTEP_OUT)                    // 2816
#define OFF_B (OFF_A + NSTEP_OUT*B_*D_)         // 47872
#define OFF_G (OFF_B + NSTEP_OUT*B_*D_)         // 92928

__device__ __forceinline__ float sigm(float v) { return 1.0f / (1.0f + expf(-v)); }
__device__ __forceinline__ float dot4(float4 a, float4 b) {
    return a.x*b.x + a.y*b.y + a.z*b.z + a.w*b.w;
}

// ---------------------------------------------------------------------------
// K1: var-LSTM gates.  gate[b,d,k] = act( sum_h h_var[b,d,h]*W[d,h,k] + x[b,t,d]*U[d,k] + B[d,k] )
// grid (2 khalf, 4 gate, 16 d), 256 threads, tile M=64(b) N=64(k) K=128(h)
// ---------------------------------------------------------------------------
__global__ __launch_bounds__(256) void k_gates(
    const float* __restrict__ hv, const float* __restrict__ x,
    const float* __restrict__ Wj, const float* __restrict__ Wi, const float* __restrict__ Wf, const float* __restrict__ Wo,
    const float* __restrict__ Uj, const float* __restrict__ Ui, const float* __restrict__ Uf, const float* __restrict__ Uo,
    const float* __restrict__ Bj, const float* __restrict__ Bi, const float* __restrict__ Bf, const float* __restrict__ Bo,
    float* __restrict__ gates, int t)
{
    const int kh = blockIdx.x, g = blockIdx.y, d = blockIdx.z;
    const int k0 = kh * 64;
    const float* W  = (g==0?Wj:(g==1?Wi:(g==2?Wf:Wo))) + (size_t)d*H_*H_;
    const float* U  = (g==0?Uj:(g==1?Ui:(g==2?Uf:Uo))) + d*H_;
    const float* Bp = (g==0?Bj:(g==1?Bi:(g==2?Bf:Bo))) + d*H_;

    __shared__ __align__(16) float hsT[128][68];   // [h][b], padded
    __shared__ __align__(16) float Ws[64][64];     // [h-chunk][k]

    const int tid = threadIdx.x;
    for (int e = tid; e < 64*128; e += 256) {
        int b2 = e >> 7, h2 = e & 127;
        hsT[h2][b2] = hv[(b2*D_ + d)*H_ + h2];
    }
    const int tb = tid >> 4, tk = tid & 15;
    float acc[4][4] = {};

    for (int hc = 0; hc < 2; hc++) {
        __syncthreads();
        for (int e = tid; e < 64*64; e += 256) {
            int h2 = e >> 6, kk = e & 63;
            Ws[h2][kk] = W[(hc*64 + h2)*H_ + k0 + kk];
        }
        __syncthreads();
        for (int h2 = 0; h2 < 64; h2++) {
            float4 hb = *(const float4*)&hsT[hc*64 + h2][tb*4];
            float4 wk = *(const float4*)&Ws[h2][tk*4];
            float hbv[4] = {hb.x, hb.y, hb.z, hb.w};
            float wkv[4] = {wk.x, wk.y, wk.z, wk.w};
            #pragma unroll
            for (int a2 = 0; a2 < 4; a2++)
                #pragma unroll
                for (int c2 = 0; c2 < 4; c2++)
                    acc[a2][c2] += hbv[a2] * wkv[c2];
        }
    }

    float u4[4], bp4[4];
    #pragma unroll
    for (int c2 = 0; c2 < 4; c2++) { u4[c2] = U[k0 + tk*4 + c2]; bp4[c2] = Bp[k0 + tk*4 + c2]; }

    #pragma unroll
    for (int a2 = 0; a2 < 4; a2++) {
        int b2 = tb*4 + a2;
        float xv = x[(b2*T_ + t)*D_ + d];
        float4 o;
        float pre[4];
        #pragma unroll
        for (int c2 = 0; c2 < 4; c2++) pre[c2] = acc[a2][c2] + xv*u4[c2] + bp4[c2];
        if (g == 0) { o.x = tanhf(pre[0]); o.y = tanhf(pre[1]); o.z = tanhf(pre[2]); o.w = tanhf(pre[3]); }
        else        { o.x = sigm(pre[0]);  o.y = sigm(pre[1]);  o.z = sigm(pre[2]);  o.w = sigm(pre[3]); }
        *(float4*)&gates[(size_t)g*(B_*D_*H_) + (b2*D_ + d)*H_ + k0 + tk*4] = o;
    }
}

// ---------------------------------------------------------------------------
// K2: var-LSTM state update; writes h_prev and delta into phi[:, 0:32, :]
// ---------------------------------------------------------------------------
__global__ __launch_bounds__(256) void k_vupd(
    float* __restrict__ hv, float* __restrict__ cv,
    const float* __restrict__ gates, float* __restrict__ phi)
{
    const int BDH = B_*D_*H_;
    int idx = blockIdx.x*256 + threadIdx.x;
    float jv = gates[idx], iv = gates[BDH + idx], fv = gates[2*BDH + idx], ov = gates[3*BDH + idx];
    float c  = cv[idx];
    float cn = c*fv + iv*jv;
    float hn = ov * tanhf(cn);
    float ho = hv[idx];
    cv[idx] = cn; hv[idx] = hn;
    int b2 = idx >> 11, r = idx & 2047, d2 = r >> 7, h2 = r & 127;
    float* pb = phi + (size_t)b2*(KK_*H_);
    pb[d2*H_ + h2]        = ho;        // phi_long
    pb[(D_+d2)*H_ + h2]   = hn - ho;   // phi_short
}

// ---------------------------------------------------------------------------
// K3: mix-LSTM gates + state. grid B_, 128 threads.
// ---------------------------------------------------------------------------
__global__ __launch_bounds__(128) void k_mix(
    const float* __restrict__ x, const float* __restrict__ h_mix,
    float* __restrict__ c_mix, float* __restrict__ hml,
    const float* __restrict__ uj, const float* __restrict__ ui, const float* __restrict__ uf, const float* __restrict__ uo,
    const float* __restrict__ wj, const float* __restrict__ wi, const float* __restrict__ wf, const float* __restrict__ wo,
    const float* __restrict__ bj, const float* __restrict__ bi, const float* __restrict__ bf, const float* __restrict__ bo,
    int t)
{
    int b = blockIdx.x, n = threadIdx.x;
    __shared__ float xs[D_];
    __shared__ float hs[NU_];
    if (n < D_) xs[n] = x[(b*T_ + t)*D_ + n];
    hs[n] = h_mix[b*NU_ + n];
    __syncthreads();
    float aj = bj[n], ai = bi[n], af = bf[n], ao = bo[n];
    #pragma unroll
    for (int d2 = 0; d2 < D_; d2++) {
        float xv = xs[d2];
        aj += xv*uj[d2*NU_ + n]; ai += xv*ui[d2*NU_ + n];
        af += xv*uf[d2*NU_ + n]; ao += xv*uo[d2*NU_ + n];
    }
    for (int m = 0; m < NU_; m++) {
        float hvv = hs[m];
        aj += hvv*wj[m*NU_ + n]; ai += hvv*wi[m*NU_ + n];
        af += hvv*wf[m*NU_ + n]; ao += hvv*wo[m*NU_ + n];
    }
    float jv = tanhf(aj), iv = sigm(ai), fv = sigm(af), ov = sigm(ao);
    float cn = fv*c_mix[b*NU_ + n] + iv*jv;
    c_mix[b*NU_ + n] = cn;
    hml[b*NU_ + n]   = ov*tanhf(cn);
}

// ---------------------------------------------------------------------------
// K4: fused qkv -> multi-head attention -> z, a_t. grid B_, 256 threads.
// ---------------------------------------------------------------------------
__global__ __launch_bounds__(256) void k_attn(
    const float* __restrict__ hv, const float* __restrict__ Wqkv,
    const float* __restrict__ Wout, float* __restrict__ z, float* __restrict__ at_g)
{
    const int b = blockIdx.x, tid = threadIdx.x;
    __shared__ __align__(16) float hs[16][128];
    __shared__ __align__(16) float qk[16][384];
    __shared__ __align__(16) float sc[8][16][16];
    __shared__ __align__(16) float cx[16][128];

    for (int e = tid; e < 2048; e += 256) hs[e>>7][e&127] = hv[b*2048 + e];
    __syncthreads();

    // qkv = h_var @ Wqkv^T
    for (int m = tid; m < 384; m += 256) {
        const float4* wr = (const float4*)(Wqkv + (size_t)m*H_);
        float acc[16] = {};
        for (int i4 = 0; i4 < 32; i4++) {
            float4 w4 = wr[i4];
            #pragma unroll
            for (int r = 0; r < 16; r++)
                acc[r] += dot4(w4, *(const float4*)&hs[r][i4*4]);
        }
        #pragma unroll
        for (int r = 0; r < 16; r++) qk[r][m] = acc[r];
    }
    __syncthreads();

    // scores
    for (int e = tid; e < 2048; e += 256) {
        int hh2 = e >> 8, qd = (e >> 4) & 15, kd = e & 15;
        float s = 0.f;
        #pragma unroll
        for (int ee = 0; ee < 16; ee++) s += qk[qd][hh2*16+ee] * qk[kd][128 + hh2*16+ee];
        sc[hh2][qd][kd] = s * 0.25f;
    }
    __syncthreads();

    // softmax + threshold per (head,row)
    if (tid < 128) {
        int hh2 = tid >> 4, qd = tid & 15;
        float mx = -1e30f;
        #pragma unroll
        for (int kd = 0; kd < 16; kd++) mx = fmaxf(mx, sc[hh2][qd][kd]);
        float ex[16]; float s = 0.f;
        #pragma unroll
        for (int kd = 0; kd < 16; kd++) { ex[kd] = expf(sc[hh2][qd][kd] - mx); s += ex[kd]; }
        float inv = 1.0f / s;
        #pragma unroll
        for (int kd = 0; kd < 16; kd++) {
            float a = ex[kd]*inv;
            sc[hh2][qd][kd] = (a >= THR_) ? a : 0.0f;
        }
    }
    __syncthreads();

    // a_t = mean over heads
    {
        int qd = tid >> 4, kd = tid & 15;
        float s = 0.f;
        #pragma unroll
        for (int hh2 = 0; hh2 < 8; hh2++) s += sc[hh2][qd][kd];
        at_g[b*256 + qd*16 + kd] = s * 0.125f;
    }

    // ctx
    for (int e = tid; e < 2048; e += 256) {
        int qd = e >> 7, c = e & 127, hh2 = c >> 4, ee = c & 15;
        float s = 0.f;
        #pragma unroll
        for (int kd = 0; kd < 16; kd++) s += sc[hh2][qd][kd] * qk[kd][256 + hh2*16 + ee];
        cx[qd][c] = s;
    }
    __syncthreads();

    // z = ctx @ Wout^T
    {
        int h = tid & 127, half = tid >> 7;
        const float4* wr = (const float4*)(Wout + (size_t)h*H_);
        float acc[8] = {};
        for (int i4 = 0; i4 < 32; i4++) {
            float4 w4 = wr[i4];
            #pragma unroll
            for (int r = 0; r < 8; r++)
                acc[r] += dot4(w4, *(const float4*)&cx[half*8 + r][i4*4]);
        }
        #pragma unroll
        for (int r = 0; r < 8; r++) z[b*2048 + (half*8 + r)*H_ + h] = acc[r];
    }
}

// ---------------------------------------------------------------------------
// K5: psi GEMM -> phi_inter.  grid (5 pair-chunks, B_), 256 threads.
// ---------------------------------------------------------------------------
__global__ __launch_bounds__(256) void k_psi(
    const float* __restrict__ z, const float* __restrict__ at,
    const float* __restrict__ Wpsi, const float* __restrict__ bpsi,
    float* __restrict__ phi)
{
    const int pc = blockIdx.x, b = blockIdx.y;
    const int p0 = pc * 48;
    __shared__ __align__(16) float zs[16][128];
    __shared__ __align__(16) float pr[48][128];
    const int tid = threadIdx.x;

    for (int e = tid; e < 2048; e += 256) zs[e>>7][e&127] = z[b*2048 + e];
    __syncthreads();
    for (int e = tid; e < 48*128; e += 256) {
        int pp = e >> 7, c = e & 127;
        int p = p0 + pp, ip = p/15, jj2 = p%15, jp = jj2 + (jj2 >= ip ? 1 : 0);
        pr[pp][c] = zs[ip][c] * zs[jp][c];
    }
    __syncthreads();

    const int h = tid & 127, pg = tid >> 7;
    const float4* wr = (const float4*)(Wpsi + (size_t)h*H_);
    float bb = bpsi[h];
    float acc[24] = {};
    for (int i4 = 0; i4 < 32; i4++) {
        float4 w4 = wr[i4];
        #pragma unroll
        for (int r = 0; r < 24; r++)
            acc[r] += dot4(w4, *(const float4*)&pr[pg*24 + r][i4*4]);
    }
    float* phb = phi + (size_t)b*(KK_*H_);
    #pragma unroll
    for (int r = 0; r < 24; r++) {
        int pp = pg*24 + r, p = p0 + pp;
        int ip = p/15, jj2 = p%15, jp = jj2 + (jj2 >= ip ? 1 : 0);
        float wat = at[b*256 + ip*16 + jp];
        phb[(2*D_ + p)*H_ + h] = tanhf(acc[r] + bb) * wat;
    }
}

// ---------------------------------------------------------------------------
// K6: Gram  G = Phi Phi^T + lam*I  (128x128 per batch).  grid (4 tiles, B_).
// ---------------------------------------------------------------------------
__global__ __launch_bounds__(256) void k_gram(const float* __restrict__ phi, float* __restrict__ G)
{
    const int tile = blockIdx.x, b = blockIdx.y;
    const int r0 = (tile >> 1) << 6, c0 = (tile & 1) << 6;
    __shared__ __align__(16) float prt[16][64];
    __shared__ __align__(16) float pct[16][64];
    const float* pb = phi + (size_t)b*(KK_*H_);
    const int tid = threadIdx.x;
    const int tr = tid >> 4, tc = tid & 15;
    float acc[4][4] = {};

    for (int kt = 0; kt < 17; kt++) {
        for (int e = tid; e < 16*64; e += 256) {
            int kk = e >> 6, rr = e & 63;
            prt[kk][rr] = pb[(kt*16 + kk)*H_ + r0 + rr];
            pct[kk][rr] = pb[(kt*16 + kk)*H_ + c0 + rr];
        }
        __syncthreads();
        #pragma unroll
        for (int kk = 0; kk < 16; kk++) {
            float4 a4 = *(const float4*)&prt[kk][tr*4];
            float4 b4 = *(const float4*)&pct[kk][tc*4];
            float av[4] = {a4.x, a4.y, a4.z, a4.w};
            float bv[4] = {b4.x, b4.y, b4.z, b4.w};
            #pragma unroll
            for (int i = 0; i < 4; i++)
                #pragma unroll
                for (int j = 0; j < 4; j++)
                    acc[i][j] += av[i]*bv[j];
        }
        __syncthreads();
    }
    #pragma unroll
    for (int i = 0; i < 4; i++) {
        int r = r0 + tr*4 + i;
        float4 o;
        float v[4];
        #pragma unroll
        for (int j = 0; j < 4; j++) {
            int c = c0 + tc*4 + j;
            v[j] = acc[i][j] + ((r == c) ? LAM_ : 0.0f);
        }
        o.x = v[0]; o.y = v[1]; o.z = v[2]; o.w = v[3];
        *(float4*)&G[(size_t)b*16384 + r*128 + c0 + tc*4] = o;
    }
}

// ---------------------------------------------------------------------------
// K7: per-batch LDLT factor + solve (Woodbury) + finalize outputs. grid B_.
// ---------------------------------------------------------------------------
__global__ __launch_bounds__(256) void k_solve(
    const float* __restrict__ G, const float* __restrict__ phi,
    const float* __restrict__ hml, float* __restrict__ h_mix,
    const float* __restrict__ w_p, const float* __restrict__ b_p,
    float* __restrict__ out, int t)
{
    const int b = blockIdx.x, tid = threadIdx.x;
    __shared__ float As[128][129];
    __shared__ __align__(16) float rv[128];
    __shared__ float idg[128];
    __shared__ float hm[128];
    __shared__ float part[128];

    for (int e = tid; e < 16384; e += 256) As[e >> 7][e & 127] = G[(size_t)b*16384 + e];
    if (tid < 128) { float v = hml[b*128 + tid]; hm[tid] = v; rv[tid] = v; }
    __syncthreads();

    // LDLT factor (raw storage: col j keeps L[i][j]*d_j ; idg[j] = 1/d_j)
    const int ti = tid >> 4, tc2 = tid & 15;
    for (int j = 0; j < 128; j++) {
        float invd = 1.0f / As[j][j];
        if (tid == 0) idg[j] = invd;
        for (int i = j + 1 + ti; i < 128; i += 16) {
            float lij = As[i][j] * invd;
            for (int c = j + 1 + tc2; c <= i; c += 16)
                As[i][c] -= lij * As[c][j];
        }
        __syncthreads();
    }

    // forward: L z = r (unit lower)
    for (int j = 0; j < 127; j++) {
        float s = rv[j] * idg[j];
        for (int i = j + 1 + tid; i < 128; i += 256)
            rv[i] -= As[i][j] * s;
        __syncthreads();
    }
    // w = D^{-1} z
    if (tid < 128) rv[tid] *= idg[tid];
    __syncthreads();
    // backward: L^T y = w
    for (int j = 127; j > 0; j--) {
        float yj = rv[j];
        for (int i = tid; i < j; i += 256)
            rv[i] -= As[j][i] * idg[i] * yj;
        __syncthreads();
    }

    // finalize: h_hat = hm - lam*y ; h_mix update ; outputs
    if (tid < 128) {
        float y = rv[tid];
        float hhat = hm[tid] - LAM_ * y;
        h_mix[b*128 + tid] = (t > 2) ? hhat : hm[tid];
        part[tid] = hhat * w_p[tid];
    }
    __syncthreads();

    if (t >= 3) {
        int ts = t - 3;
        if (tid == 0) {
            float s = 0.f;
            for (int h2 = 0; h2 < 128; h2++) s += part[h2];
            out[b*NSTEP_OUT + ts] = s + b_p[0];
        }
        const float* pb = phi + (size_t)b*(KK_*H_);
        for (int k = tid; k < KK_; k += 256) {
            const float4* col = (const float4*)(pb + (size_t)k*H_);
            float th = 0.f;
            for (int i4 = 0; i4 < 32; i4++) {
                float4 c4 = col[i4];
                float4 y4 = *(const float4*)&rv[i4*4];
                th += dot4(c4, y4);
            }
            if (k < D_)
                out[OFF_A + ts*(B_*D_) + b*D_ + k] = th;
            else if (k < 2*D_)
                out[OFF_B + ts*(B_*D_) + b*D_ + (k - D_)] = th;
            else {
                int p = k - 2*D_;
                int ip = p/15, jj2 = p%15, jp = jj2 + (jj2 >= ip ? 1 : 0);
                out[OFF_G + ts*(B_*D_*D_) + b*(D_*D_) + ip*D_ + jp] = th;
            }
        }
        if (tid < D_)
            out[OFF_G + ts*(B_*D_*D_) + b*(D_*D_) + tid*D_ + tid] = 0.0f;
    }
}

// ---------------------------------------------------------------------------
extern "C" void kernel_launch(void* const* d_in, const int* in_sizes, int n_in,
                              void* d_out, int out_size, void* d_ws, size_t ws_size,
                              hipStream_t stream) {
    const float* x    = (const float*)d_in[0];
    const float* W_j  = (const float*)d_in[1];
    const float* W_i  = (const float*)d_in[2];
    const float* W_f  = (const float*)d_in[3];
    const float* W_o  = (const float*)d_in[4];
    const float* U_j  = (const float*)d_in[5];
    const float* U_i  = (const float*)d_in[6];
    const float* U_f  = (const float*)d_in[7];
    const float* U_o  = (const float*)d_in[8];
    const float* B_j  = (const float*)d_in[9];
    const float* B_i  = (const float*)d_in[10];
    const float* B_f  = (const float*)d_in[11];
    const float* B_o  = (const float*)d_in[12];
    const float* u_j  = (const float*)d_in[13];
    const float* u_i  = (const float*)d_in[14];
    const float* u_f  = (const float*)d_in[15];
    const float* u_o  = (const float*)d_in[16];
    const float* w_j  = (const float*)d_in[17];
    const float* w_i  = (const float*)d_in[18];
    const float* w_f  = (const float*)d_in[19];
    const float* w_o  = (const float*)d_in[20];
    const float* b_j  = (const float*)d_in[21];
    const float* b_i  = (const float*)d_in[22];
    const float* b_f  = (const float*)d_in[23];
    const float* b_o  = (const float*)d_in[24];
    const float* W_qkv= (const float*)d_in[25];
    const float* W_out= (const float*)d_in[26];
    const float* W_psi= (const float*)d_in[27];
    const float* b_psi= (const float*)d_in[28];
    const float* w_p  = (const float*)d_in[29];
    const float* b_p  = (const float*)d_in[30];

    float* ws = (float*)d_ws;
    float* h_var = ws;                       // 131072
    float* c_var = h_var + 131072;           // 131072
    float* h_mix = c_var + 131072;           // 8192
    float* c_mix = h_mix + 8192;             // 8192
    float* hml   = c_mix + 8192;             // 8192
    float* gates = hml + 8192;               // 524288
    float* phi   = gates + 524288;           // 2228224
    float* zbuf  = phi + 2228224;            // 131072
    float* atbuf = zbuf + 131072;            // 16384
    float* Gw    = atbuf + 16384;            // 1048576

    // zero-init LSTM state (h_var, c_var, h_mix, c_mix are contiguous)
    hipMemsetAsync(ws, 0, (size_t)278528 * sizeof(float), stream);

    float* out = (float*)d_out;

    for (int t = 0; t < T_ - 1; t++) {
        k_gates<<<dim3(2, 4, 16), 256, 0, stream>>>(
            h_var, x, W_j, W_i, W_f, W_o, U_j, U_i, U_f, U_o, B_j, B_i, B_f, B_o, gates, t);
        k_vupd<<<512, 256, 0, stream>>>(h_var, c_var, gates, phi);
        k_mix<<<B_, 128, 0, stream>>>(
            x, h_mix, c_mix, hml, u_j, u_i, u_f, u_o, w_j, w_i, w_f, w_o, b_j, b_i, b_f, b_o, t);
        k_attn<<<B_, 256, 0, stream>>>(h_var, W_qkv, W_out, zbuf, atbuf);
        k_psi<<<dim3(5, B_), 256, 0, stream>>>(zbuf, atbuf, W_psi, b_psi, phi);
        k_gram<<<dim3(4, B_), 256, 0, stream>>>(phi, Gw);
        k_solve<<<B_, 256, 0, stream>>>(Gw, phi, hml, h_mix, w_p, b_p, out, t);
    }
}

// Round 2
// 8608.315 us; speedup vs baseline: 1.6556x; 1.6556x over previous
//
#include <hip/hip_runtime.h>
#include <hip/hip_bf16.h>
#include <math.h>

#define B_ 64
#define T_ 48
#define D_ 16
#define H_ 128
#define NU_ 128
#define HEADS_ 8
#define HD_ 16
#define P_ 240
#define KK_ 272
#define LAM_ 0.01f
#define THR_ 0.01f

// output offsets (floats)
#define NSTEP_OUT 44
#define OFF_A (B_*NSTEP_OUT)                    // 2816
#define OFF_B (OFF_A + NSTEP_OUT*B_*D_)         // 47872
#define OFF_G (OFF_B + NSTEP_OUT*B_*D_)         // 92928

__device__ __forceinline__ float sigm(float v) { return 1.0f / (1.0f + expf(-v)); }
__device__ __forceinline__ float dot4(float4 a, float4 b) {
    return a.x*b.x + a.y*b.y + a.z*b.z + a.w*b.w;
}

// ---------------------------------------------------------------------------
// K1: fused var-gates GEMM (blocks 0..127) + mix-LSTM (blocks 128..191).
// ---------------------------------------------------------------------------
__global__ __launch_bounds__(256) void k_front(
    const float* __restrict__ hv, const float* __restrict__ x,
    const float* __restrict__ Wj, const float* __restrict__ Wi, const float* __restrict__ Wf, const float* __restrict__ Wo,
    const float* __restrict__ Uj, const float* __restrict__ Ui, const float* __restrict__ Uf, const float* __restrict__ Uo,
    const float* __restrict__ Bj, const float* __restrict__ Bi, const float* __restrict__ Bf, const float* __restrict__ Bo,
    float* __restrict__ gates,
    const float* __restrict__ h_mix, float* __restrict__ c_mix, float* __restrict__ hml,
    const float* __restrict__ uj, const float* __restrict__ ui, const float* __restrict__ uf, const float* __restrict__ uo,
    const float* __restrict__ wj, const float* __restrict__ wi, const float* __restrict__ wf, const float* __restrict__ wo,
    const float* __restrict__ bj, const float* __restrict__ bi, const float* __restrict__ bf_, const float* __restrict__ bo,
    int t)
{
    const int tid = threadIdx.x;
    const int bx = blockIdx.x;

    if (bx < 128) {
        // ----- var-gate GEMM tile: kh = bx&1, g = (bx>>1)&3, d = bx>>3 -----
        const int kh = bx & 1, g = (bx >> 1) & 3, d = bx >> 3;
        const int k0 = kh * 64;
        const float* W  = (g==0?Wj:(g==1?Wi:(g==2?Wf:Wo))) + (size_t)d*H_*H_;
        const float* U  = (g==0?Uj:(g==1?Ui:(g==2?Uf:Uo))) + d*H_;
        const float* Bp = (g==0?Bj:(g==1?Bi:(g==2?Bf:Bo))) + d*H_;

        __shared__ __align__(16) float hsT[128][68];   // [h][b], padded
        __shared__ __align__(16) float Ws[64][64];     // [h-chunk][k]

        for (int e = tid; e < 64*128; e += 256) {
            int b2 = e >> 7, h2 = e & 127;
            hsT[h2][b2] = hv[(b2*D_ + d)*H_ + h2];
        }
        const int tb = tid >> 4, tk = tid & 15;
        float acc[4][4] = {};

        for (int hc = 0; hc < 2; hc++) {
            __syncthreads();
            for (int e = tid; e < 64*64; e += 256) {
                int h2 = e >> 6, kk = e & 63;
                Ws[h2][kk] = W[(hc*64 + h2)*H_ + k0 + kk];
            }
            __syncthreads();
            for (int h2 = 0; h2 < 64; h2++) {
                float4 hb = *(const float4*)&hsT[hc*64 + h2][tb*4];
                float4 wk = *(const float4*)&Ws[h2][tk*4];
                float hbv[4] = {hb.x, hb.y, hb.z, hb.w};
                float wkv[4] = {wk.x, wk.y, wk.z, wk.w};
                #pragma unroll
                for (int a2 = 0; a2 < 4; a2++)
                    #pragma unroll
                    for (int c2 = 0; c2 < 4; c2++)
                        acc[a2][c2] += hbv[a2] * wkv[c2];
            }
        }

        float u4[4], bp4[4];
        #pragma unroll
        for (int c2 = 0; c2 < 4; c2++) { u4[c2] = U[k0 + tk*4 + c2]; bp4[c2] = Bp[k0 + tk*4 + c2]; }

        #pragma unroll
        for (int a2 = 0; a2 < 4; a2++) {
            int b2 = tb*4 + a2;
            float xv = x[(b2*T_ + t)*D_ + d];
            float4 o;
            float pre[4];
            #pragma unroll
            for (int c2 = 0; c2 < 4; c2++) pre[c2] = acc[a2][c2] + xv*u4[c2] + bp4[c2];
            if (g == 0) { o.x = tanhf(pre[0]); o.y = tanhf(pre[1]); o.z = tanhf(pre[2]); o.w = tanhf(pre[3]); }
            else        { o.x = sigm(pre[0]);  o.y = sigm(pre[1]);  o.z = sigm(pre[2]);  o.w = sigm(pre[3]); }
            *(float4*)&gates[(size_t)g*(B_*D_*H_) + (b2*D_ + d)*H_ + k0 + tk*4] = o;
        }
    } else {
        // ----- mix-LSTM for batch b -----
        const int b = bx - 128;
        __shared__ float xs[16];
        __shared__ float hs2[128];
        __shared__ float gj[128], gi[128], gf[128], go[128];
        const int n = tid & 127, gg = tid >> 7;
        if (tid < 16)  xs[tid]  = x[(b*T_ + t)*D_ + tid];
        if (tid < 128) hs2[tid] = h_mix[b*NU_ + tid];
        __syncthreads();

        const float* uA = gg ? uf : uj;
        const float* uB = gg ? uo : ui;
        const float* wA = gg ? wf : wj;
        const float* wB = gg ? wo : wi;
        float accA = gg ? bf_[n] : bj[n];
        float accB = gg ? bo[n]  : bi[n];
        #pragma unroll
        for (int d2 = 0; d2 < 16; ++d2) {
            float xv = xs[d2];
            accA += xv * uA[d2*NU_ + n];
            accB += xv * uB[d2*NU_ + n];
        }
        for (int m = 0; m < 128; ++m) {
            float hvv = hs2[m];
            accA += hvv * wA[m*NU_ + n];
            accB += hvv * wB[m*NU_ + n];
        }
        if (gg == 0) { gj[n] = tanhf(accA); gi[n] = sigm(accB); }
        else         { gf[n] = sigm(accA);  go[n] = sigm(accB); }
        __syncthreads();
        if (tid < 128) {
            float cn = gf[tid]*c_mix[b*NU_ + tid] + gi[tid]*gj[tid];
            c_mix[b*NU_ + tid] = cn;
            hml[b*NU_ + tid]   = go[tid]*tanhf(cn);
        }
    }
}

// ---------------------------------------------------------------------------
// K2: var-LSTM state update + phi_long/short + fused attention. grid B_.
// ---------------------------------------------------------------------------
__global__ __launch_bounds__(256) void k_attn_up(
    float* __restrict__ hv, float* __restrict__ cv,
    const float* __restrict__ gates, float* __restrict__ phi,
    const float* __restrict__ Wqkv, const float* __restrict__ Wout,
    float* __restrict__ z, float* __restrict__ at_g)
{
    const int b = blockIdx.x, tid = threadIdx.x;
    const int BDH = B_*D_*H_;
    __shared__ __align__(16) float hs[16][128];
    __shared__ __align__(16) float qk[16][384];
    __shared__ __align__(16) float sc[8][16][16];
    __shared__ __align__(16) float cx[16][128];

    float* pb = phi + (size_t)b*(KK_*H_);
    for (int e = tid; e < 2048; e += 256) {
        float jv = gates[b*2048 + e];
        float iv = gates[BDH   + b*2048 + e];
        float fv = gates[2*BDH + b*2048 + e];
        float ov = gates[3*BDH + b*2048 + e];
        float c  = cv[b*2048 + e];
        float cn = c*fv + iv*jv;
        float hn = ov * tanhf(cn);
        float ho = hv[b*2048 + e];
        cv[b*2048 + e] = cn;
        hv[b*2048 + e] = hn;
        hs[e>>7][e&127] = hn;
        pb[(e>>7)*H_ + (e&127)]        = ho;        // phi_long
        pb[(D_ + (e>>7))*H_ + (e&127)] = hn - ho;   // phi_short
    }
    __syncthreads();

    // qkv = h_var @ Wqkv^T : each thread does 3 m-cols x 8 rows
    {
        const int half = tid >> 7, mt = tid & 127;
        const float4* w0 = (const float4*)(Wqkv + (size_t)(mt*3 + 0)*H_);
        const float4* w1 = (const float4*)(Wqkv + (size_t)(mt*3 + 1)*H_);
        const float4* w2 = (const float4*)(Wqkv + (size_t)(mt*3 + 2)*H_);
        float acc[3][8] = {};
        for (int i4 = 0; i4 < 32; i4++) {
            float4 wa = w0[i4], wb = w1[i4], wc = w2[i4];
            #pragma unroll
            for (int rr = 0; rr < 8; rr++) {
                float4 h4 = *(const float4*)&hs[half*8 + rr][i4*4];
                acc[0][rr] += dot4(wa, h4);
                acc[1][rr] += dot4(wb, h4);
                acc[2][rr] += dot4(wc, h4);
            }
        }
        #pragma unroll
        for (int q = 0; q < 3; q++)
            #pragma unroll
            for (int rr = 0; rr < 8; rr++)
                qk[half*8 + rr][mt*3 + q] = acc[q][rr];
    }
    __syncthreads();

    // scores
    for (int e = tid; e < 2048; e += 256) {
        int hh2 = e >> 8, qd = (e >> 4) & 15, kd = e & 15;
        float s = 0.f;
        #pragma unroll
        for (int ee = 0; ee < 16; ee++) s += qk[qd][hh2*16+ee] * qk[kd][128 + hh2*16+ee];
        sc[hh2][qd][kd] = s * 0.25f;
    }
    __syncthreads();

    // softmax + threshold per (head,row)
    if (tid < 128) {
        int hh2 = tid >> 4, qd = tid & 15;
        float mx = -1e30f;
        #pragma unroll
        for (int kd = 0; kd < 16; kd++) mx = fmaxf(mx, sc[hh2][qd][kd]);
        float ex[16]; float s = 0.f;
        #pragma unroll
        for (int kd = 0; kd < 16; kd++) { ex[kd] = expf(sc[hh2][qd][kd] - mx); s += ex[kd]; }
        float inv = 1.0f / s;
        #pragma unroll
        for (int kd = 0; kd < 16; kd++) {
            float a = ex[kd]*inv;
            sc[hh2][qd][kd] = (a >= THR_) ? a : 0.0f;
        }
    }
    __syncthreads();

    // a_t = mean over heads
    {
        int qd = tid >> 4, kd = tid & 15;
        if (tid < 256) {
            float s = 0.f;
            #pragma unroll
            for (int hh2 = 0; hh2 < 8; hh2++) s += sc[hh2][qd][kd];
            at_g[b*256 + qd*16 + kd] = s * 0.125f;
        }
    }

    // ctx
    for (int e = tid; e < 2048; e += 256) {
        int qd = e >> 7, c = e & 127, hh2 = c >> 4, ee = c & 15;
        float s = 0.f;
        #pragma unroll
        for (int kd = 0; kd < 16; kd++) s += sc[hh2][qd][kd] * qk[kd][256 + hh2*16 + ee];
        cx[qd][c] = s;
    }
    __syncthreads();

    // z = ctx @ Wout^T
    {
        int h = tid & 127, half = tid >> 7;
        const float4* wr = (const float4*)(Wout + (size_t)h*H_);
        float acc[8] = {};
        for (int i4 = 0; i4 < 32; i4++) {
            float4 w4 = wr[i4];
            #pragma unroll
            for (int r = 0; r < 8; r++)
                acc[r] += dot4(w4, *(const float4*)&cx[half*8 + r][i4*4]);
        }
        #pragma unroll
        for (int r = 0; r < 8; r++) z[b*2048 + (half*8 + r)*H_ + h] = acc[r];
    }
}

// ---------------------------------------------------------------------------
// K3: psi GEMM -> phi_inter.  grid (5 pair-chunks, B_), 256 threads.
// ---------------------------------------------------------------------------
__global__ __launch_bounds__(256) void k_psi(
    const float* __restrict__ z, const float* __restrict__ at,
    const float* __restrict__ Wpsi, const float* __restrict__ bpsi,
    float* __restrict__ phi)
{
    const int pc = blockIdx.x, b = blockIdx.y;
    const int p0 = pc * 48;
    __shared__ __align__(16) float zs[16][128];
    __shared__ __align__(16) float pr[48][128];
    const int tid = threadIdx.x;

    for (int e = tid; e < 2048; e += 256) zs[e>>7][e&127] = z[b*2048 + e];
    __syncthreads();
    for (int e = tid; e < 48*128; e += 256) {
        int pp = e >> 7, c = e & 127;
        int p = p0 + pp, ip = p/15, jj2 = p%15, jp = jj2 + (jj2 >= ip ? 1 : 0);
        pr[pp][c] = zs[ip][c] * zs[jp][c];
    }
    __syncthreads();

    const int h = tid & 127, pg = tid >> 7;
    const float4* wr = (const float4*)(Wpsi + (size_t)h*H_);
    float bb = bpsi[h];
    float acc[24] = {};
    for (int i4 = 0; i4 < 32; i4++) {
        float4 w4 = wr[i4];
        #pragma unroll
        for (int r = 0; r < 24; r++)
            acc[r] += dot4(w4, *(const float4*)&pr[pg*24 + r][i4*4]);
    }
    float* phb = phi + (size_t)b*(KK_*H_);
    #pragma unroll
    for (int r = 0; r < 24; r++) {
        int pp = pg*24 + r, p = p0 + pp;
        int ip = p/15, jj2 = p%15, jp = jj2 + (jj2 >= ip ? 1 : 0);
        float wat = at[b*256 + ip*16 + jp];
        phb[(2*D_ + p)*H_ + h] = tanhf(acc[r] + bb) * wat;
    }
}

// ---------------------------------------------------------------------------
// K4: Gram lower triangle: G = Phi Phi^T + lam*I.  grid (3 tiles, B_).
// tiles: 0->(0,0), 1->(64,0), 2->(64,64)
// ---------------------------------------------------------------------------
__global__ __launch_bounds__(256) void k_gram(const float* __restrict__ phi, float* __restrict__ G)
{
    const int tile = blockIdx.x, b = blockIdx.y;
    const int r0 = (tile >= 1) ? 64 : 0;
    const int c0 = (tile == 2) ? 64 : 0;
    const bool diag = (r0 == c0);
    __shared__ __align__(16) float prt[16][64];
    __shared__ __align__(16) float pct[16][64];
    const float* pb = phi + (size_t)b*(KK_*H_);
    const int tid = threadIdx.x;
    const int tr = tid >> 4, tc = tid & 15;
    float acc[4][4] = {};

    for (int kt = 0; kt < 17; kt++) {
        __syncthreads();
        for (int e = tid; e < 16*64; e += 256) {
            int kk = e >> 6, rr = e & 63;
            prt[kk][rr] = pb[(kt*16 + kk)*H_ + r0 + rr];
            if (!diag) pct[kk][rr] = pb[(kt*16 + kk)*H_ + c0 + rr];
        }
        __syncthreads();
        const float* pcb = diag ? &prt[0][0] : &pct[0][0];
        #pragma unroll
        for (int kk = 0; kk < 16; kk++) {
            float4 a4 = *(const float4*)&prt[kk][tr*4];
            float4 b4 = *(const float4*)&pcb[kk*64 + tc*4];
            float av[4] = {a4.x, a4.y, a4.z, a4.w};
            float bv[4] = {b4.x, b4.y, b4.z, b4.w};
            #pragma unroll
            for (int i = 0; i < 4; i++)
                #pragma unroll
                for (int j = 0; j < 4; j++)
                    acc[i][j] += av[i]*bv[j];
        }
    }
    #pragma unroll
    for (int i = 0; i < 4; i++) {
        int r = r0 + tr*4 + i;
        float v[4];
        #pragma unroll
        for (int j = 0; j < 4; j++) {
            int c = c0 + tc*4 + j;
            v[j] = acc[i][j] + ((r == c) ? LAM_ : 0.0f);
        }
        float4 o; o.x = v[0]; o.y = v[1]; o.z = v[2]; o.w = v[3];
        *(float4*)&G[(size_t)b*16384 + r*128 + c0 + tc*4] = o;
    }
}

// ---------------------------------------------------------------------------
// K5: blocked Cholesky (16-wide panels, wave-synchronous panel factor),
// panel-blocked triangular solves, epilogue outputs. grid B_, 256 threads.
// ---------------------------------------------------------------------------
__global__ __launch_bounds__(256) void k_solve2(
    const float* __restrict__ G, const float* __restrict__ phi,
    const float* __restrict__ hml, float* __restrict__ h_mix,
    const float* __restrict__ w_p, const float* __restrict__ b_p,
    float* __restrict__ out, int t)
{
    const int b = blockIdx.x, tid = threadIdx.x;
    const int lane = tid & 63, wv = tid >> 6;
    __shared__ __align__(16) float As[128][132];   // rows 16B-aligned (132*4=528)
    __shared__ __align__(16) float rv[132];
    __shared__ float hm[128];
    __shared__ float part[128];

    for (int e = tid; e < 16384; e += 256) As[e >> 7][e & 127] = G[(size_t)b*16384 + e];
    if (tid < 128) { float v = hml[b*128 + tid]; hm[tid] = v; rv[tid] = v; }
    __syncthreads();

    // ---- blocked Cholesky (lower), panels of 16 ----
    for (int p = 0; p < 8; ++p) {
        const int s = p*16;
        if (wv == 0) {
            const int r0 = s + lane, r1 = s + lane + 64;
            const bool v0 = r0 < 128, v1 = r1 < 128;
            float a0[16], a1[16];
            #pragma unroll
            for (int k = 0; k < 16; ++k) {
                a0[k] = v0 ? As[r0][s+k] : 0.f;
                a1[k] = v1 ? As[r1][s+k] : 0.f;
            }
            #pragma unroll
            for (int j = 0; j < 16; ++j) {
                float piv = __shfl(a0[j], j);
                float dsq = sqrtf(piv);
                float inv = 1.0f / dsq;
                a0[j] = (lane == j) ? dsq : a0[j]*inv;
                a1[j] *= inv;
                for (int c = j+1; c < 16; ++c) {
                    float Lcj = __shfl(a0[j], c);
                    a0[c] -= a0[j]*Lcj;
                    a1[c] -= a1[j]*Lcj;
                }
            }
            #pragma unroll
            for (int k = 0; k < 16; ++k) {
                if (v0) As[r0][s+k] = a0[k];
                if (v1) As[r1][s+k] = a1[k];
            }
        }
        __syncthreads();
        // trailing SYRK update on lower triangle (i,j >= s+16, j<=i)
        const int s2 = s + 16;
        if (s2 < 128) {
            const int ti = tid >> 4, tj = tid & 15;
            for (int i = s2 + ti; i < 128; i += 16) {
                float Li[16];
                #pragma unroll
                for (int k4 = 0; k4 < 4; ++k4) {
                    float4 f4 = *(const float4*)&As[i][s + k4*4];
                    Li[k4*4+0]=f4.x; Li[k4*4+1]=f4.y; Li[k4*4+2]=f4.z; Li[k4*4+3]=f4.w;
                }
                for (int j = s2 + tj; j <= i; j += 16) {
                    float acc = 0.f;
                    #pragma unroll
                    for (int k4 = 0; k4 < 4; ++k4) {
                        float4 f4 = *(const float4*)&As[j][s + k4*4];
                        acc += Li[k4*4+0]*f4.x + Li[k4*4+1]*f4.y + Li[k4*4+2]*f4.z + Li[k4*4+3]*f4.w;
                    }
                    As[i][j] -= acc;
                }
            }
        }
        __syncthreads();
    }

    // ---- forward solve L y = hm ----
    for (int p = 0; p < 8; ++p) {
        const int s = p*16;
        if (wv == 0 && lane < 16) {
            float Lr[16];
            #pragma unroll
            for (int k = 0; k < 16; ++k) Lr[k] = As[s+lane][s+k];
            float r = rv[s+lane];
            float inv = 1.0f / Lr[lane];
            #pragma unroll
            for (int j = 0; j < 16; ++j) {
                if (lane == j) r *= inv;
                float yj = __shfl(r, j);
                if (lane > j) r -= Lr[j]*yj;
            }
            rv[s+lane] = r;
        }
        __syncthreads();
        int i = s + 16 + tid;
        if (i < 128) {
            float acc = rv[i];
            #pragma unroll
            for (int k = 0; k < 16; ++k) acc -= As[i][s+k]*rv[s+k];
            rv[i] = acc;
        }
        __syncthreads();
    }

    // ---- backward solve L^T x = y ----
    for (int p = 7; p >= 0; --p) {
        const int s = p*16;
        if (wv == 0 && lane < 16) {
            float Lc[16];
            #pragma unroll
            for (int k = 0; k < 16; ++k) Lc[k] = As[s+k][s+lane];
            float r = rv[s+lane];
            float inv = 1.0f / Lc[lane];
            #pragma unroll
            for (int j = 15; j >= 0; --j) {
                if (lane == j) r *= inv;
                float xj = __shfl(r, j);
                if (lane < j) r -= Lc[j]*xj;
            }
            rv[s+lane] = r;
        }
        __syncthreads();
        if (tid < s) {
            float acc = rv[tid];
            #pragma unroll
            for (int k = 0; k < 16; ++k) acc -= As[s+k][tid]*rv[s+k];
            rv[tid] = acc;
        }
        __syncthreads();
    }

    // ---- finalize: h_hat = hm - lam*y ; h_mix update ; outputs ----
    if (tid < 128) {
        float y = rv[tid];
        float hhat = hm[tid] - LAM_ * y;
        h_mix[b*128 + tid] = (t > 2) ? hhat : hm[tid];
        part[tid] = hhat * w_p[tid];
    }
    __syncthreads();

    if (t >= 3) {
        int ts = t - 3;
        if (tid < 64) {
            float s = part[tid] + part[tid + 64];
            for (int off = 32; off; off >>= 1) s += __shfl_down(s, off);
            if (tid == 0) out[b*NSTEP_OUT + ts] = s + b_p[0];
        }
        const float* pb = phi + (size_t)b*(KK_*H_);
        for (int k = tid; k < KK_; k += 256) {
            const float4* col = (const float4*)(pb + (size_t)k*H_);
            float th = 0.f;
            for (int i4 = 0; i4 < 32; i4++) {
                float4 c4 = col[i4];
                float4 y4 = *(const float4*)&rv[i4*4];
                th += dot4(c4, y4);
            }
            if (k < D_)
                out[OFF_A + ts*(B_*D_) + b*D_ + k] = th;
            else if (k < 2*D_)
                out[OFF_B + ts*(B_*D_) + b*D_ + (k - D_)] = th;
            else {
                int p = k - 2*D_;
                int ip = p/15, jj2 = p%15, jp = jj2 + (jj2 >= ip ? 1 : 0);
                out[OFF_G + ts*(B_*D_*D_) + b*(D_*D_) + ip*D_ + jp] = th;
            }
        }
        if (tid < D_)
            out[OFF_G + ts*(B_*D_*D_) + b*(D_*D_) + tid*D_ + tid] = 0.0f;
    }
}

// ---------------------------------------------------------------------------
extern "C" void kernel_launch(void* const* d_in, const int* in_sizes, int n_in,
                              void* d_out, int out_size, void* d_ws, size_t ws_size,
                              hipStream_t stream) {
    const float* x    = (const float*)d_in[0];
    const float* W_j  = (const float*)d_in[1];
    const float* W_i  = (const float*)d_in[2];
    const float* W_f  = (const float*)d_in[3];
    const float* W_o  = (const float*)d_in[4];
    const float* U_j  = (const float*)d_in[5];
    const float* U_i  = (const float*)d_in[6];
    const float* U_f  = (const float*)d_in[7];
    const float* U_o  = (const float*)d_in[8];
    const float* B_j  = (const float*)d_in[9];
    const float* B_i  = (const float*)d_in[10];
    const float* B_f  = (const float*)d_in[11];
    const float* B_o  = (const float*)d_in[12];
    const float* u_j  = (const float*)d_in[13];
    const float* u_i  = (const float*)d_in[14];
    const float* u_f  = (const float*)d_in[15];
    const float* u_o  = (const float*)d_in[16];
    const float* w_j  = (const float*)d_in[17];
    const float* w_i  = (const float*)d_in[18];
    const float* w_f  = (const float*)d_in[19];
    const float* w_o  = (const float*)d_in[20];
    const float* b_j  = (const float*)d_in[21];
    const float* b_i  = (const float*)d_in[22];
    const float* b_f  = (const float*)d_in[23];
    const float* b_o  = (const float*)d_in[24];
    const float* W_qkv= (const float*)d_in[25];
    const float* W_out= (const float*)d_in[26];
    const float* W_psi= (const float*)d_in[27];
    const float* b_psi= (const float*)d_in[28];
    const float* w_p  = (const float*)d_in[29];
    const float* b_p  = (const float*)d_in[30];

    float* ws = (float*)d_ws;
    float* h_var = ws;                       // 131072
    float* c_var = h_var + 131072;           // 131072
    float* h_mix = c_var + 131072;           // 8192
    float* c_mix = h_mix + 8192;             // 8192
    float* hml   = c_mix + 8192;             // 8192
    float* gates = hml + 8192;               // 524288
    float* phi   = gates + 524288;           // 2228224
    float* zbuf  = phi + 2228224;            // 131072
    float* atbuf = zbuf + 131072;            // 16384
    float* Gw    = atbuf + 16384;            // 1048576

    // zero-init LSTM state (h_var, c_var, h_mix, c_mix are contiguous)
    hipMemsetAsync(ws, 0, (size_t)278528 * sizeof(float), stream);

    float* out = (float*)d_out;

    for (int t = 0; t < T_ - 1; t++) {
        k_front<<<192, 256, 0, stream>>>(
            h_var, x, W_j, W_i, W_f, W_o, U_j, U_i, U_f, U_o, B_j, B_i, B_f, B_o, gates,
            h_mix, c_mix, hml, u_j, u_i, u_f, u_o, w_j, w_i, w_f, w_o, b_j, b_i, b_f, b_o, t);
        k_attn_up<<<B_, 256, 0, stream>>>(h_var, c_var, gates, phi, W_qkv, W_out, zbuf, atbuf);
        k_psi<<<dim3(5, B_), 256, 0, stream>>>(zbuf, atbuf, W_psi, b_psi, phi);
        k_gram<<<dim3(3, B_), 256, 0, stream>>>(phi, Gw);
        k_solve2<<<B_, 256, 0, stream>>>(Gw, phi, hml, h_mix, w_p, b_p, out, t);
    }
}